// Round 7
// baseline (223.620 us; speedup 1.0000x reference)
//
#include <hip/hip_runtime.h>

// PSAMask collect: out[(nh*97+nw)*9409 + h*97 + w] = x[(nh-h+48)*97 + (nw-w+48)][h][w]
// (valid window, else 0). Pure permutation -> memory-bound.
//
// R7 (extends H11): block = (nh, h-QUAD). Planes a0-p (p=0..3) for rows h0+p
// all staged into LDS (150,544 B -> 1 block/CU), ONE vmcnt(0) drain, then each
// of the 97 output channels receives a CONTIGUOUS 4-row 1552 B run written by
// consecutive lanes/instructions -> long write bursts, halved seam sectors.
// Grid = (chunk, nh): co-resident blocks write a contiguous output window.
// LDS source-swizzled per plane: lds[p][b*97 + (w+b)%97] = x[b][w] -> the
// diagonal read (b = nw-w+48, col (nw+48)%97) has lane bank delta -1.

#define HW    97
#define PLANE 9409      // 97*97
#define HALF  48
#define NT    512
#define NITER 19        // ceil(PLANE/NT); 9409 = 18*512 + 193
#define RUN4  388       // 4*97 floats per channel run
#define TOT4  37636     // 4*PLANE
#define WITER 74        // ceil(TOT4/NT); 37636 = 73*512 + 259

typedef const __attribute__((address_space(1))) void* gptr_t;
typedef __attribute__((address_space(3))) void* lptr_t;

__global__ __launch_bounds__(NT)
void psamask_collect_kernel(const float* __restrict__ x, float* __restrict__ out) {
    const int c  = blockIdx.x;          // 0..24 (h-quads; c=24 is the single row h=96)
    const int nh = blockIdx.y;          // 0..96
    const int h0 = 4 * c;
    const unsigned tid = threadIdx.x;

    const unsigned r0 = tid / HW;       // 0..5
    const unsigned c0 = tid - r0 * HW;

    __shared__ float lds[4 * PLANE];    // 150,544 B -> 1 block/CU

    const int a0 = nh - h0 + HALF;
    const int TH = (h0 == 96) ? 1 : 4;

    // ---- stage up to 4 planes (async DMA, source-swizzled), single drain
    #pragma unroll
    for (int p = 0; p < 4; ++p) {
        if (p >= TH || (unsigned)(a0 - p) >= HW) continue;
        const float* __restrict__ xp =
            x + (size_t)((unsigned)(a0 - p) * HW) * PLANE + (unsigned)(h0 + p) * HW;
        unsigned b = r0, cw = c0;        // flat dest d = b*97 + cw
        #pragma unroll
        for (int k = 0; k < NITER; ++k) {
            unsigned d = tid + (unsigned)k * NT;
            if (d < PLANE) {
                unsigned w = cw - b + ((cw < b) ? HW : 0u);       // (cw-b) mod 97
                const float* g = xp + b * PLANE + w;              // per-lane source
                unsigned d0 = (unsigned)p * PLANE + (unsigned)k * NT + (tid & ~63u);
                __builtin_amdgcn_global_load_lds((gptr_t)g, (lptr_t)&lds[d0], 4, 0, 0);
            }
            b += 5; cw += 27;            // 512 = 5*97 + 27
            if (cw >= HW) { cw -= HW; b += 1; }
        }
    }
    asm volatile("s_waitcnt vmcnt(0)" ::: "memory");
    __syncthreads();

    float* __restrict__ outp =
        out + (size_t)((unsigned)nh * HW) * PLANE + (unsigned)h0 * HW;

    const bool av0 = ((unsigned)a0       < HW);
    const bool av1 = ((unsigned)(a0 - 1) < HW);
    const bool av2 = ((unsigned)(a0 - 2) < HW);
    const bool av3 = ((unsigned)(a0 - 3) < HW);

    if (TH == 4) {
        // elements p = q*388 + e over all 97 channels' contiguous 4-row runs
        unsigned q   = (tid >= RUN4) ? 1u : 0u;
        unsigned e   = tid - q * RUN4;
        unsigned cw  = q + HALF;                         // (q+48) < 97 here
        unsigned off = q * PLANE + e;
        #pragma unroll 2
        for (int k = 0; k < WITER; ++k) {
            unsigned d = tid + (unsigned)k * NT;
            if (d < TOT4) {
                unsigned hp = (e >= 194u) ? ((e >= 291u) ? 3u : 2u)
                                          : ((e >= 97u)  ? 1u : 0u);
                unsigned w  = e - hp * HW;
                int b = (int)q - (int)w + HALF;          // nw - w + 48
                bool vb = ((unsigned)b < HW);
                unsigned bc = vb ? (unsigned)b : 0u;
                float v = lds[hp * PLANE + bc * HW + cw];
                bool av = (hp == 0u) ? av0 : (hp == 1u) ? av1 : (hp == 2u) ? av2 : av3;
                outp[off] = (vb && av) ? v : 0.0f;
            }
            // p += 512 = 1*388 + 124
            e += 124u; q += 1u; cw += 1u; off += PLANE + 124u;
            if (e >= RUN4) { e -= RUN4; q += 1u; cw += 1u; off += PLANE - RUN4; }
            if (cw >= HW) cw -= HW;
        }
    } else {
        // last chunk: single row h = 96
        unsigned w   = c0;
        int      b   = (int)r0 - (int)c0 + HALF;
        unsigned cw  = r0 + HALF; if (cw >= HW) cw -= HW;
        unsigned off = r0 * PLANE + c0;
        #pragma unroll
        for (int k = 0; k < NITER; ++k) {
            unsigned d = tid + (unsigned)k * NT;
            if (d < PLANE) {
                bool vb = ((unsigned)b < HW);
                unsigned bc = vb ? (unsigned)b : 0u;
                float v = lds[bc * HW + cw];
                outp[off] = (vb && av0) ? v : 0.0f;
            }
            w += 27;
            bool wrap = (w >= HW);
            if (wrap) w -= HW;
            b  += wrap ? 76 : -22;
            cw += wrap ? 6u : 5u;
            if (cw >= HW) cw -= HW;
            off += wrap ? (6u * PLANE - 70u) : (5u * PLANE + 27u);
        }
    }
}

extern "C" void kernel_launch(void* const* d_in, const int* in_sizes, int n_in,
                              void* d_out, int out_size, void* d_ws, size_t ws_size,
                              hipStream_t stream) {
    const float* x = (const float*)d_in[0];
    float* out = (float*)d_out;
    dim3 grid(25, HW);   // (h-quad chunk, nh): co-resident blocks share an output window
    psamask_collect_kernel<<<grid, NT, 0, stream>>>(x, out);
}

// Round 8
// 158.061 us; speedup vs baseline: 1.4148x; 1.4148x over previous
//
#include <hip/hip_runtime.h>

// PSAMask collect: out[(nh*97+nw)*9409 + h*97 + w] = x[(nh-h+48)*97 + (nw-w+48)][h][w]
// (valid window, else 0). Pure permutation -> memory-bound.
//
// R8 = R6 (h-pair blocks, 2 planes in LDS, 2 blocks/CU, 776 B write runs)
// + XCD-pinned write windows: block ℓ -> XCD k=ℓ%8; XCD k owns nh ∈ {k,k+8,..},
// all 49 h-chunks of one nh consecutive on that XCD. Channel seam lines merge
// in ONE L2 (no cross-XCD partial-line flushes) and each XCD writes a dense
// private ~3.7 MB window (DRAM row locality). R7 proved 4-row runs reach the
// 354 MB write ideal but 1 block/CU serializes phases; R6's 2-block overlap
// is worth more. Reads ride shared L3.
// LDS source-swizzled per plane: lds[p][b*97 + (w+b)%97] = x[b][w] ->
// diagonal read (b = nw-w+48, col (nw+48)%97) has lane bank delta -1.

#define HW    97
#define PLANE 9409      // 97*97
#define HALF  48
#define NT    512
#define NITER 19        // ceil(PLANE/NT); 9409 = 18*512 + 193
#define RUN   194       // 2*97 floats per channel run
#define TOT2  18818     // 2*PLANE
#define WITER 37        // ceil(TOT2/NT); 18818 = 36*512 + 386

typedef const __attribute__((address_space(1))) void* gptr_t;
typedef __attribute__((address_space(3))) void* lptr_t;

__global__ __launch_bounds__(NT)
void psamask_collect_kernel(const float* __restrict__ x, float* __restrict__ out) {
    // ---- XCD-pinned decode: k = XCD digit -> nh = 8*g + k, c sweeps within nh
    const unsigned l = blockIdx.x;
    const unsigned k8 = l & 7u;
    const unsigned m  = l >> 3;          // 0..636
    const unsigned g  = m / 49u;
    const unsigned c  = m - g * 49u;     // 0..48 (h-pair chunk)
    const int nh = (int)(g * 8u + k8);
    if (nh > 96) return;                 // padded blocks

    const int h0 = 2 * (int)c;
    const int TH = (h0 == 96) ? 1 : 2;
    const unsigned tid = threadIdx.x;

    const unsigned r0 = tid / HW;        // 0..5
    const unsigned c0 = tid - r0 * HW;

    __shared__ float lds[2 * PLANE];     // 75,272 B -> 2 blocks/CU

    const int a0 = nh - h0 + HALF;
    const bool av0 = ((unsigned)a0 < HW);
    const bool av1 = (TH == 2) && ((unsigned)(a0 - 1) < HW);

    // ---- stage up to 2 planes (async DMA, source-swizzled), single drain
    #pragma unroll
    for (int p = 0; p < 2; ++p) {
        const bool av = p ? av1 : av0;
        if (!av) continue;
        const float* __restrict__ xp =
            x + (size_t)((unsigned)(a0 - p) * HW) * PLANE + (unsigned)(h0 + p) * HW;
        unsigned b = r0, cw = c0;        // flat dest d = b*97 + cw
        #pragma unroll
        for (int kk = 0; kk < NITER; ++kk) {
            unsigned d = tid + (unsigned)kk * NT;
            if (d < PLANE) {
                unsigned w = cw - b + ((cw < b) ? HW : 0u);       // (cw-b) mod 97
                const float* gsrc = xp + b * PLANE + w;           // per-lane source
                unsigned d0 = (unsigned)p * PLANE + (unsigned)kk * NT + (tid & ~63u);
                __builtin_amdgcn_global_load_lds((gptr_t)gsrc, (lptr_t)&lds[d0], 4, 0, 0);
            }
            b += 5; cw += 27;            // 512 = 5*97 + 27
            if (cw >= HW) { cw -= HW; b += 1; }
        }
    }
    asm volatile("s_waitcnt vmcnt(0)" ::: "memory");
    __syncthreads();

    float* __restrict__ outp =
        out + (size_t)((unsigned)nh * HW) * PLANE + (unsigned)h0 * HW;

    if (TH == 2) {
        // elements p = q*194 + e over all 97 channels' contiguous 2-row runs
        unsigned q  = (tid >= RUN ? 1u : 0u) + (tid >= 2u * RUN ? 1u : 0u);
        unsigned e  = tid - q * RUN;
        unsigned cw = q + HALF;                          // (q+48), q0<=2 so <97
        unsigned off = q * PLANE + e;
        #pragma unroll
        for (int kk = 0; kk < WITER; ++kk) {
            unsigned d = tid + (unsigned)kk * NT;
            if (d < TOT2) {
                unsigned hp = (e >= HW) ? 1u : 0u;       // which plane/row
                unsigned w  = e - hp * HW;
                int b = (int)q - (int)w + HALF;          // nw - w + 48
                bool vb = ((unsigned)b < HW);
                unsigned bc = vb ? (unsigned)b : 0u;
                float v = lds[hp * PLANE + bc * HW + cw];
                bool av = hp ? av1 : av0;
                outp[off] = (vb && av) ? v : 0.0f;
            }
            // p += 512 = 2*194 + 124
            e += 124u; q += 2u; cw += 2u; off += 2u * PLANE + 124u;
            if (e >= RUN) { e -= RUN; q += 1u; cw += 1u; off += PLANE - RUN; }
            if (cw >= HW) cw -= HW;
        }
    } else {
        // last chunk: single row h = 96
        unsigned w   = c0;
        int      b   = (int)r0 - (int)c0 + HALF;
        unsigned cw  = r0 + HALF; if (cw >= HW) cw -= HW;
        unsigned off = r0 * PLANE + c0;
        #pragma unroll
        for (int kk = 0; kk < NITER; ++kk) {
            unsigned d = tid + (unsigned)kk * NT;
            if (d < PLANE) {
                bool vb = ((unsigned)b < HW);
                unsigned bc = vb ? (unsigned)b : 0u;
                float v = lds[bc * HW + cw];
                outp[off] = (vb && av0) ? v : 0.0f;
            }
            w += 27;
            bool wrap = (w >= HW);
            if (wrap) w -= HW;
            b  += wrap ? 76 : -22;
            cw += wrap ? 6u : 5u;
            if (cw >= HW) cw -= HW;
            off += wrap ? (6u * PLANE - 70u) : (5u * PLANE + 27u);
        }
    }
}

extern "C" void kernel_launch(void* const* d_in, const int* in_sizes, int n_in,
                              void* d_out, int out_size, void* d_ws, size_t ws_size,
                              hipStream_t stream) {
    const float* x = (const float*)d_in[0];
    float* out = (float*)d_out;
    // 8 XCD digits x 637 (= 13*49) inner slots; nh>96 blocks early-exit (+7% pad)
    psamask_collect_kernel<<<dim3(5096), NT, 0, stream>>>(x, out);
}